// Round 11
// baseline (590.580 us; speedup 1.0000x reference)
//
#include <hip/hip_runtime.h>

// Problem constants
#define N_ROWS 131072    // 32*4096
#define D 64
#define K_CODES 1024

typedef _Float16 f16x8 __attribute__((ext_vector_type(8)));
typedef float    f32x4 __attribute__((ext_vector_type(4)));

#define MFMA16(a, b, c) __builtin_amdgcn_mfma_f32_16x16x32_f16((a), (b), (c), 0, 0, 0)

// ---------------------------------------------------------------------------
// ws layout: csqr[1024] f32 (4 KB) | CBf: 16384 f16x8 units (256 KB)
// CBf unit index = tile*256 + f*64 + lane, f in {0:hi k0-31, 1:hi k32-63,
// 2:lo k0-31, 3:lo k32-63}; unit holds the 8 halves lane needs for that
// MFMA B fragment: B[k=(lane>>4)*8+j][n=lane&15], code = tile*16 + n.
// ---------------------------------------------------------------------------
__global__ __launch_bounds__(256)
void prep_kernel(const float* __restrict__ CB, _Float16* __restrict__ CBf,
                 float* __restrict__ csqr, float* __restrict__ loss) {
    const int b = blockIdx.x, t = threadIdx.x;
    if (b < 64) {
        const int unit = b * 256 + t;
        const int tile = unit >> 8;
        const int f    = (unit >> 6) & 3;
        const int lane = unit & 63;
        const int quad = lane >> 4, lrow = lane & 15;
        const int code = tile * 16 + lrow;
        const int k0   = (f & 1) * 32 + quad * 8;
        const float* src = CB + (size_t)code * D + k0;
        float4 v0 = *(const float4*)(src);
        float4 v1 = *(const float4*)(src + 4);
        float xs[8] = {v0.x, v0.y, v0.z, v0.w, v1.x, v1.y, v1.z, v1.w};
        f16x8 o;
#pragma unroll
        for (int j = 0; j < 8; ++j) {
            _Float16 h = (_Float16)xs[j];
            o[j] = (f < 2) ? h : (_Float16)(xs[j] - (float)h);
        }
        *(f16x8*)(CBf + (size_t)unit * 8) = o;
    } else {
        if (t == 0) *loss = 0.0f;
        for (int k = t; k < K_CODES; k += 256) {
            const float4* p = (const float4*)(CB + (size_t)k * D);
            float s = 0.0f;
#pragma unroll
            for (int i = 0; i < 16; ++i) {
                float4 v = p[i];
                s += v.x * v.x + v.y * v.y + v.z * v.z + v.w * v.w;
            }
            csqr[k] = s;
        }
    }
}

// ---------------------------------------------------------------------------
// K1: split-f16 MFMA argmin + fused z_q + loss  (R9 structure, residency
// experiment: launch_bounds 2nd arg 3 -> 6. Cross-round counter data shows
// resident waves/CU tracks this arg (2->7, 3->8.6, 4->13 waves), NOT the
// VGPR limit (84 VGPR fits 24 waves/CU). VGPR budget at 6/EU = 85 >= 84,
// so codegen is unchanged — pure TLP increase.)
// Block = 64 rows, 4 waves partitioned as (row-half, code-half):
//   wave w: rows [R0 + (w>>1)*32, +32) x codes [(w&1)*512, +512)  (32 tiles).
// A = (-2x) hi/lo in regs (MT=2). B streamed from fragment-ordered CBf
// (L2-resident), 4-buffer register prefetch with sched_barrier pins.
// score = |c|^2 + (-2x)·c, acc-init = csqr, 6 MFMAs/tile/mt (hh,lh,hl;
// ll ~2^-24 dropped). Cross-wave merge via LDS (code-half 0 has smaller
// indices -> '<' keeps np.argmin first-min). Epilogue: block-cooperative
// contiguous zq span write (16B-aligned despite out+1).
// ---------------------------------------------------------------------------
__global__ __launch_bounds__(256, 6)
void argmin_kernel(const float* __restrict__ X,
                   const _Float16* __restrict__ CBf,
                   const float* __restrict__ csqr,
                   const float* __restrict__ CB,
                   float* __restrict__ out) {
    __shared__ float LsC[K_CODES];       // csqr copy, 4 KB
    __shared__ float candD[64][2];
    __shared__ int   candI[64][2];
    __shared__ int   ivfin[64];
    __shared__ float xsqW[2];

    const int t    = threadIdx.x;
    const int wave = t >> 6;
    const int lane = t & 63;
    const int lrow = lane & 15;
    const int quad = lane >> 4;
    const int rh   = wave >> 1;          // row half
    const int ch   = wave & 1;           // code half
    const int R0   = blockIdx.x * 64;
    const int Rw   = R0 + rh * 32;

    // Stage csqr to LDS (covered by the barrier below).
    ((float4*)LsC)[t] = ((const float4*)csqr)[t];

    // ---- A fragments: (-2x) split hi/lo; xsq accumulated (ch==0 waves
    // contribute so each block element is counted exactly once).
    // A layout: lane holds A[m=lane&15][k=quad*8+j], j=0..7.
    f16x8 Ah[2][2], Al[2][2];
    float xsq = 0.0f;
#pragma unroll
    for (int mt = 0; mt < 2; ++mt) {
        const float* xr = X + (size_t)(Rw + mt * 16 + lrow) * D;
#pragma unroll
        for (int ks = 0; ks < 2; ++ks) {
            const int k0 = ks * 32 + quad * 8;
            float4 v0 = *(const float4*)(xr + k0);
            float4 v1 = *(const float4*)(xr + k0 + 4);
            float xs[8] = {v0.x, v0.y, v0.z, v0.w, v1.x, v1.y, v1.z, v1.w};
            f16x8 h, l;
#pragma unroll
            for (int j = 0; j < 8; ++j) {
                xsq += xs[j] * xs[j];
                float sv = -2.0f * xs[j];
                _Float16 hh = (_Float16)sv;
                h[j] = hh;
                l[j] = (_Float16)(sv - (float)hh);
            }
            Ah[mt][ks] = h;
            Al[mt][ks] = l;
        }
    }
    __syncthreads();   // LsC ready

    float bestd[2][4];
    int   besti[2][4];
#pragma unroll
    for (int mt = 0; mt < 2; ++mt)
#pragma unroll
        for (int r = 0; r < 4; ++r) { bestd[mt][r] = 3.0e38f; besti[mt][r] = 0; }

    // Wave's code range starts at tile ch*32.
    const f16x8* gw = (const f16x8*)CBf + (size_t)ch * 32 * 256 + lane;

#define LOADB(Bv, tl)                                                         \
    do {                                                                      \
        const f16x8* _p = gw + (tl) * 256;                                    \
        Bv[0] = _p[0]; Bv[1] = _p[64]; Bv[2] = _p[128]; Bv[3] = _p[192];      \
        __builtin_amdgcn_sched_barrier(0); /* pin: loads may not sink */      \
    } while (0)

#define COMPUTE(Bv, tl)                                                       \
    do {                                                                      \
        const int   c  = (ch * 32 + (tl)) * 16 + lrow;                        \
        const float cs = LsC[c];                                              \
        _Pragma("unroll")                                                     \
        for (int mt = 0; mt < 2; ++mt) {                                      \
            f32x4 acc = {cs, cs, cs, cs};                                     \
            acc = MFMA16(Ah[mt][0], Bv[0], acc);                              \
            acc = MFMA16(Ah[mt][1], Bv[1], acc);                              \
            acc = MFMA16(Al[mt][0], Bv[0], acc);                              \
            acc = MFMA16(Al[mt][1], Bv[1], acc);                              \
            acc = MFMA16(Ah[mt][0], Bv[2], acc);                              \
            acc = MFMA16(Ah[mt][1], Bv[3], acc);                              \
            _Pragma("unroll")                                                 \
            for (int r = 0; r < 4; ++r) {                                     \
                bool lt = acc[r] < bestd[mt][r];                              \
                bestd[mt][r] = lt ? acc[r] : bestd[mt][r];                    \
                besti[mt][r] = lt ? c : besti[mt][r];                         \
            }                                                                 \
        }                                                                     \
    } while (0)

    // 32 local tiles, 4-buffer register pipeline, distance-3 prefetch with
    // pinned load order. Overrun prefetches wrap via &31 (tiles reloaded
    // but never computed) so every load stays inside CBf. Codes ascend with
    // tl for fixed lane -> strict < keeps first minimum (np.argmin).
    f16x8 B0[4], B1[4], B2[4], B3[4];
    LOADB(B0, 0);
    LOADB(B1, 1);
    LOADB(B2, 2);
    for (int tl = 0; tl < 32; tl += 4) {
        LOADB(B3, (tl + 3) & 31);
        COMPUTE(B0, tl);
        LOADB(B0, (tl + 4) & 31);
        COMPUTE(B1, tl + 1);
        LOADB(B1, (tl + 5) & 31);
        COMPUTE(B2, tl + 2);
        LOADB(B2, (tl + 6) & 31);
        COMPUTE(B3, tl + 3);
    }

    // ---- xsq: reduce within ch==0 waves (each block element once).
    if (ch == 0) {
        float s = xsq;
#pragma unroll
        for (int m = 1; m < 64; m <<= 1) s += __shfl_xor(s, m, 64);
        if (lane == 0) xsqW[rh] = s;
    }

    // ---- In-wave argmin reduce across the 16 code-columns (lexicographic
    // on exact ties), deposit per-row candidate for this code half.
#pragma unroll
    for (int mt = 0; mt < 2; ++mt) {
#pragma unroll
        for (int r = 0; r < 4; ++r) {
            float dv = bestd[mt][r];
            int   iv = besti[mt][r];
#pragma unroll
            for (int m = 1; m < 16; m <<= 1) {
                float od = __shfl_xor(dv, m, 64);
                int   oi = __shfl_xor(iv, m, 64);
                if (od < dv || (od == dv && oi < iv)) { dv = od; iv = oi; }
            }
            if (lrow == 0) {
                int rl = rh * 32 + mt * 16 + quad * 4 + r;   // 0..63
                candD[rl][ch] = dv;
                candI[rl][ch] = iv;
            }
        }
    }
    __syncthreads();

    // ---- Merge the two code halves; write idxf; accumulate loss.
    const float scale = 1.25f / (float)((size_t)N_ROWS * D);
    if (t < 64) {
        float d0 = candD[t][0], d1 = candD[t][1];
        int   i0 = candI[t][0], i1 = candI[t][1];
        // ch0 indices are all < ch1 indices -> tie keeps ch0 (first min).
        bool take1 = d1 < d0;
        float dv = take1 ? d1 : d0;
        int   iv = take1 ? i1 : i0;
        out[1 + (size_t)N_ROWS * D + R0 + t] = (float)iv;   // idxf
        ivfin[t] = iv;
        float ssum = dv;
#pragma unroll
        for (int m = 1; m < 64; m <<= 1) ssum += __shfl_xor(ssum, m, 64);
        if (t == 0)
            atomicAdd(out, (ssum + xsqW[0] + xsqW[1]) * scale);
    }
    __syncthreads();

    // ---- Block-cooperative zq span write: dwords [R0*64, R0*64+4096) at
    // out+1. Global dword offset 1+R0*64+j is 16B-aligned iff j%4==3.
    float* p = out + 1 + (size_t)R0 * D;
#pragma unroll
    for (int i = 0; i < 4; ++i) {
        int q = i * 256 + t;        // 0..1023
        int j = 4 * q + 3;          // 3,7,...,4095
        if (q < 1023) {
            float v[4];
#pragma unroll
            for (int e = 0; e < 4; ++e) {
                int jj = j + e;     // may straddle a row boundary
                v[e] = CB[(size_t)ivfin[jj >> 6] * D + (jj & 63)];
            }
            *(float4*)(p + j) = make_float4(v[0], v[1], v[2], v[3]);
        } else if (q == 1023) {
            p[4095] = CB[(size_t)ivfin[63] * D + 63];
        }
    }
    if (t == 0) {   // head dwords j=0..2 (row 0, cols 0..2)
        const float* c0 = CB + (size_t)ivfin[0] * D;
        p[0] = c0[0];
        p[1] = c0[1];
        p[2] = c0[2];
    }
}

// ---------------------------------------------------------------------------
extern "C" void kernel_launch(void* const* d_in, const int* in_sizes, int n_in,
                              void* d_out, int out_size, void* d_ws,
                              size_t ws_size, hipStream_t stream) {
    const float* X  = (const float*)d_in[0];   // inputs  [131072,64]
    const float* CB = (const float*)d_in[1];   // codebook [1024,64]

    float*    csqr = (float*)d_ws;                      // 4 KB
    _Float16* CBf  = (_Float16*)((char*)d_ws + 4096);   // 256 KB

    hipLaunchKernelGGL(prep_kernel, dim3(65), dim3(256), 0, stream,
                       CB, CBf, csqr, (float*)d_out);
    hipLaunchKernelGGL(argmin_kernel, dim3(N_ROWS / 64), dim3(256), 0, stream,
                       X, CBf, csqr, CB, (float*)d_out);
}

// Round 12
// 201.275 us; speedup vs baseline: 2.9342x; 2.9342x over previous
//
#include <hip/hip_runtime.h>

// Problem constants
#define N_ROWS 131072    // 32*4096
#define D 64
#define K_CODES 1024

typedef _Float16 f16x8 __attribute__((ext_vector_type(8)));
typedef float    f32x4 __attribute__((ext_vector_type(4)));

#define MFMA16(a, b, c) __builtin_amdgcn_mfma_f32_16x16x32_f16((a), (b), (c), 0, 0, 0)

// ---------------------------------------------------------------------------
// ws layout: csqr[1024] f32 (4 KB) | CBf 256 KB | keys[131072] u64 (1 MB)
// CBf unit index = tile*256 + f*64 + lane, f in {0:hi k0-31, 1:hi k32-63,
// 2:lo k0-31, 3:lo k32-63}; unit holds the 8 halves lane needs for the
// MFMA B fragment: B[k=(lane>>4)*8+j][n=lane&15], code = tile*16 + n.
// keys[row] = (monotone_map(dist) << 32) | index  -> atomicMin == argmin
// with first-min tie-break (smaller index wins on equal distance).
// ---------------------------------------------------------------------------
__global__ __launch_bounds__(256)
void prep_kernel(const float* __restrict__ CB, _Float16* __restrict__ CBf,
                 float* __restrict__ csqr, unsigned long long* __restrict__ keys,
                 float* __restrict__ loss) {
    const int b = blockIdx.x, t = threadIdx.x;
    if (b < 64) {
        const int unit = b * 256 + t;
        const int tile = unit >> 8;
        const int f    = (unit >> 6) & 3;
        const int lane = unit & 63;
        const int quad = lane >> 4, lrow = lane & 15;
        const int code = tile * 16 + lrow;
        const int k0   = (f & 1) * 32 + quad * 8;
        const float* src = CB + (size_t)code * D + k0;
        float4 v0 = *(const float4*)(src);
        float4 v1 = *(const float4*)(src + 4);
        float xs[8] = {v0.x, v0.y, v0.z, v0.w, v1.x, v1.y, v1.z, v1.w};
        f16x8 o;
#pragma unroll
        for (int j = 0; j < 8; ++j) {
            _Float16 h = (_Float16)xs[j];
            o[j] = (f < 2) ? h : (_Float16)(xs[j] - (float)h);
        }
        *(f16x8*)(CBf + (size_t)unit * 8) = o;
    } else if (b == 64) {
        if (t == 0) *loss = 0.0f;
        for (int k = t; k < K_CODES; k += 256) {
            const float4* p = (const float4*)(CB + (size_t)k * D);
            float s = 0.0f;
#pragma unroll
            for (int i = 0; i < 16; ++i) {
                float4 v = p[i];
                s += v.x * v.x + v.y * v.y + v.z * v.z + v.w * v.w;
            }
            csqr[k] = s;
        }
    } else {   // b in [65, 65+512): init argmin keys to +inf
        keys[(size_t)(b - 65) * 256 + t] = 0xFFFFFFFFFFFFFFFFULL;
    }
}

// ---------------------------------------------------------------------------
// K1: LDS-resident-B split-f16 MFMA argmin. Grid = (512 row-groups, 4 code
// quarters). Block = 512 threads (8 waves): stages its quarter (256 codes,
// 64 KB fragment-ordered) into LDS ONCE -> one barrier -> waves free-run:
// wave w owns rows [R0+w*32,+32) (MT=2) x 16 tiles from LDS. ds_read
// latency ~120cyc ~= one tile's issue window, so the compiler's natural
// depth-1 scheduling suffices (R7/R9 lesson: it won't keep deeper register
// pipelines; L2-latency ~400-600cyc needed depth 4-5 -> unreachable).
// LDS 65 KB -> 2 blocks/CU = 16 waves/CU (~2x R9's residency).
// score = |c|^2 + (-2x)·c, acc-init = csqr, 6 MFMAs/tile/mt (hh,lh,hl;
// ll ~2^-24 dropped). Cross-quarter merge: per-row atomicMin on packed
// (mapped-dist, idx) u64 -> exact np.argmin first-min semantics.
// ---------------------------------------------------------------------------
__global__ __launch_bounds__(512, 4)
void argmin_kernel(const float* __restrict__ X,
                   const _Float16* __restrict__ CBf,
                   const float* __restrict__ csqr,
                   unsigned long long* __restrict__ keys,
                   float* __restrict__ out) {
    __shared__ __align__(16) _Float16 Bs[16 * 256 * 8];   // 64 KB
    __shared__ float LsC[256];                            // quarter csqr

    const int t    = threadIdx.x;
    const int wave = t >> 6;             // 0..7
    const int lane = t & 63;
    const int lrow = lane & 15;
    const int quad = lane >> 4;
    const int cq   = blockIdx.y;         // code quarter
    const int R0   = blockIdx.x * 256;
    const int Rw   = R0 + wave * 32;

    // Stage quarter csqr (64 float4) and the 64 KB B quarter (4096 units).
    if (t < 64) ((float4*)LsC)[t] = ((const float4*)(csqr + cq * 256))[t];
    {
        const f16x8* src = (const f16x8*)CBf + (size_t)cq * 4096;
        f16x8* dst = (f16x8*)Bs;
#pragma unroll
        for (int i = 0; i < 8; ++i) dst[i * 512 + t] = src[i * 512 + t];
    }

    // ---- A fragments: (-2x) split hi/lo; xsq covers this wave's 32 rows
    // exactly once (only cq==0 blocks contribute it to the loss).
    // A layout: lane holds A[m=lane&15][k=quad*8+j], j=0..7.
    f16x8 Ah[2][2], Al[2][2];
    float xsq = 0.0f;
#pragma unroll
    for (int mt = 0; mt < 2; ++mt) {
        const float* xr = X + (size_t)(Rw + mt * 16 + lrow) * D;
#pragma unroll
        for (int ks = 0; ks < 2; ++ks) {
            const int k0 = ks * 32 + quad * 8;
            float4 v0 = *(const float4*)(xr + k0);
            float4 v1 = *(const float4*)(xr + k0 + 4);
            float xs[8] = {v0.x, v0.y, v0.z, v0.w, v1.x, v1.y, v1.z, v1.w};
            f16x8 h, l;
#pragma unroll
            for (int j = 0; j < 8; ++j) {
                xsq += xs[j] * xs[j];
                float sv = -2.0f * xs[j];
                _Float16 hh = (_Float16)sv;
                h[j] = hh;
                l[j] = (_Float16)(sv - (float)hh);
            }
            Ah[mt][ks] = h;
            Al[mt][ks] = l;
        }
    }
    __syncthreads();   // Bs + LsC ready; the ONLY barrier

    float bestd[2][4];
    int   besti[2][4];
#pragma unroll
    for (int mt = 0; mt < 2; ++mt)
#pragma unroll
        for (int r = 0; r < 4; ++r) { bestd[mt][r] = 3.0e38f; besti[mt][r] = 0; }

    // 16 tiles from LDS; contiguous-lane ds_read_b128 (conflict-free).
    // Codes ascend with tl for fixed lane -> strict < keeps first minimum.
#pragma unroll 2
    for (int tl = 0; tl < 16; ++tl) {
        const f16x8* bu = (const f16x8*)Bs + tl * 256 + lane;
        f16x8 Bh0 = bu[0], Bh1 = bu[64], Bl0 = bu[128], Bl1 = bu[192];
        const int   cc = cq * 256 + tl * 16 + lrow;
        const float cs = LsC[tl * 16 + lrow];
#pragma unroll
        for (int mt = 0; mt < 2; ++mt) {
            f32x4 acc = {cs, cs, cs, cs};   // score = |c|^2 + (-2x)·c
            acc = MFMA16(Ah[mt][0], Bh0, acc);
            acc = MFMA16(Ah[mt][1], Bh1, acc);
            acc = MFMA16(Al[mt][0], Bh0, acc);
            acc = MFMA16(Al[mt][1], Bh1, acc);
            acc = MFMA16(Ah[mt][0], Bl0, acc);
            acc = MFMA16(Ah[mt][1], Bl1, acc);
#pragma unroll
            for (int r = 0; r < 4; ++r) {
                bool lt = acc[r] < bestd[mt][r];
                bestd[mt][r] = lt ? acc[r] : bestd[mt][r];
                besti[mt][r] = lt ? cc : besti[mt][r];
            }
        }
    }

    // ---- xsq into loss (quarter-0 blocks only; each row element once).
    if (cq == 0) {
        float s = xsq;
#pragma unroll
        for (int m = 1; m < 64; m <<= 1) s += __shfl_xor(s, m, 64);
        if (lane == 0)
            atomicAdd(out, s * (1.25f / (float)((size_t)N_ROWS * D)));
    }

    // ---- In-wave argmin reduce across the 16 code-columns (lexicographic
    // on exact ties), then per-row atomicMin with the packed key.
#pragma unroll
    for (int mt = 0; mt < 2; ++mt) {
#pragma unroll
        for (int r = 0; r < 4; ++r) {
            float dv = bestd[mt][r];
            int   iv = besti[mt][r];
#pragma unroll
            for (int m = 1; m < 16; m <<= 1) {
                float od = __shfl_xor(dv, m, 64);
                int   oi = __shfl_xor(iv, m, 64);
                if (od < dv || (od == dv && oi < iv)) { dv = od; iv = oi; }
            }
            if (lrow == 0) {
                int row = Rw + mt * 16 + quad * 4 + r;
                unsigned ub = __float_as_uint(dv);
                ub = (ub & 0x80000000u) ? ~ub : (ub | 0x80000000u);
                unsigned long long key =
                    ((unsigned long long)ub << 32) | (unsigned)iv;
                atomicMin(&keys[row], key);
            }
        }
    }
}

// ---------------------------------------------------------------------------
// K2: unpack keys -> idxf + loss(ssum) + block-cooperative aligned zq write.
// Block = 256 threads handles 256 rows.
// ---------------------------------------------------------------------------
__global__ __launch_bounds__(256)
void finish_kernel(const float* __restrict__ CB,
                   const unsigned long long* __restrict__ keys,
                   float* __restrict__ out) {
    __shared__ int   ivfin[256];
    __shared__ float red[256];
    const int t  = threadIdx.x;
    const int R0 = blockIdx.x * 256;

    unsigned long long key = keys[R0 + t];
    int      iv = (int)(key & 0xFFFFFFFFu);
    unsigned ud = (unsigned)(key >> 32);
    unsigned bb = (ud & 0x80000000u) ? (ud ^ 0x80000000u) : ~ud;
    float    dv = __uint_as_float(bb);
    ivfin[t] = iv;
    out[1 + (size_t)N_ROWS * D + R0 + t] = (float)iv;   // idxf
    red[t] = dv;
    __syncthreads();
    for (int s = 128; s > 0; s >>= 1) {
        if (t < s) red[t] += red[t + s];
        __syncthreads();
    }
    if (t == 0)
        atomicAdd(out, red[0] * (1.25f / (float)((size_t)N_ROWS * D)));

    // zq span: dwords [R0*64, R0*64+16384) at out+1; 16B-aligned iff j%4==3.
    float* p = out + 1 + (size_t)R0 * D;
#pragma unroll
    for (int i = 0; i < 16; ++i) {
        int q = i * 256 + t;        // 0..4095
        int j = 4 * q + 3;
        if (q < 4095) {
            float v[4];
#pragma unroll
            for (int e = 0; e < 4; ++e) {
                int jj = j + e;     // may straddle a row boundary
                v[e] = CB[(size_t)ivfin[jj >> 6] * D + (jj & 63)];
            }
            *(float4*)(p + j) = make_float4(v[0], v[1], v[2], v[3]);
        } else {
            p[16383] = CB[(size_t)ivfin[255] * D + 63];
        }
    }
    if (t == 0) {   // head dwords j=0..2 (row 0, cols 0..2)
        const float* c0 = CB + (size_t)ivfin[0] * D;
        p[0] = c0[0];
        p[1] = c0[1];
        p[2] = c0[2];
    }
}

// ---------------------------------------------------------------------------
extern "C" void kernel_launch(void* const* d_in, const int* in_sizes, int n_in,
                              void* d_out, int out_size, void* d_ws,
                              size_t ws_size, hipStream_t stream) {
    const float* X  = (const float*)d_in[0];   // inputs  [131072,64]
    const float* CB = (const float*)d_in[1];   // codebook [1024,64]

    float*    csqr = (float*)d_ws;                            // 4 KB
    _Float16* CBf  = (_Float16*)((char*)d_ws + 4096);         // 256 KB
    unsigned long long* keys =
        (unsigned long long*)((char*)d_ws + 4096 + 262144);   // 1 MB

    hipLaunchKernelGGL(prep_kernel, dim3(65 + 512), dim3(256), 0, stream,
                       CB, CBf, csqr, keys, (float*)d_out);
    hipLaunchKernelGGL(argmin_kernel, dim3(512, 4), dim3(512), 0, stream,
                       X, CBf, csqr, keys, (float*)d_out);
    hipLaunchKernelGGL(finish_kernel, dim3(512), dim3(256), 0, stream,
                       CB, keys, (float*)d_out);
}

// Round 13
// 156.716 us; speedup vs baseline: 3.7685x; 1.2843x over previous
//
#include <hip/hip_runtime.h>

// Problem constants
#define N_ROWS 131072    // 32*4096
#define D 64
#define K_CODES 1024

typedef _Float16 f16x8 __attribute__((ext_vector_type(8)));
typedef float    f32x4 __attribute__((ext_vector_type(4)));

#define MFMA16(a, b, c) __builtin_amdgcn_mfma_f32_16x16x32_f16((a), (b), (c), 0, 0, 0)

// ---------------------------------------------------------------------------
// ws layout: csqr[1024] f32 (4 KB) | CBf: 16384 f16x8 units (256 KB)
// CBf unit index = tile*256 + f*64 + lane, f in {0:hi k0-31, 1:hi k32-63,
// 2:lo k0-31, 3:lo k32-63}; unit holds the 8 halves lane needs for that
// MFMA B fragment: B[k=(lane>>4)*8+j][n=lane&15], code = tile*16 + n.
// ---------------------------------------------------------------------------
__global__ __launch_bounds__(256)
void prep_kernel(const float* __restrict__ CB, _Float16* __restrict__ CBf,
                 float* __restrict__ csqr, float* __restrict__ loss) {
    const int b = blockIdx.x, t = threadIdx.x;
    if (b < 64) {
        const int unit = b * 256 + t;
        const int tile = unit >> 8;
        const int f    = (unit >> 6) & 3;
        const int lane = unit & 63;
        const int quad = lane >> 4, lrow = lane & 15;
        const int code = tile * 16 + lrow;
        const int k0   = (f & 1) * 32 + quad * 8;
        const float* src = CB + (size_t)code * D + k0;
        float4 v0 = *(const float4*)(src);
        float4 v1 = *(const float4*)(src + 4);
        float xs[8] = {v0.x, v0.y, v0.z, v0.w, v1.x, v1.y, v1.z, v1.w};
        f16x8 o;
#pragma unroll
        for (int j = 0; j < 8; ++j) {
            _Float16 h = (_Float16)xs[j];
            o[j] = (f < 2) ? h : (_Float16)(xs[j] - (float)h);
        }
        *(f16x8*)(CBf + (size_t)unit * 8) = o;
    } else {
        if (t == 0) *loss = 0.0f;
        for (int k = t; k < K_CODES; k += 256) {
            const float4* p = (const float4*)(CB + (size_t)k * D);
            float s = 0.0f;
#pragma unroll
            for (int i = 0; i < 16; ++i) {
                float4 v = p[i];
                s += v.x * v.x + v.y * v.y + v.z * v.z + v.w * v.w;
            }
            csqr[k] = s;
        }
    }
}

// ---------------------------------------------------------------------------
// K1: split-f16 MFMA argmin + fused z_q + loss, ASM-PINNED deep prefetch.
// Block = 64 rows, 4 waves partitioned as (row-half, code-half):
//   wave w: rows [R0 + (w>>1)*32, +32) x codes [(w&1)*512, +512)  (32 tiles).
// A = (-2x) hi/lo in regs (MT=2). B streamed from fragment-ordered CBf
// (L2-resident) via INLINE-ASM global_load_dwordx4 into 4 register buffers
// (distance-3) with hand-placed s_waitcnt vmcnt(12) (hipBLASLt pattern:
// fine-grained vmcnt, never 0). R7/R9/R11 evidence: source-level pipelines
// get collapsed by the compiler (VGPR stuck at 84 = depth ~1); asm defs
// cannot be sunk, forcing the 64-VGPR pipeline to exist.
// vmcnt bookkeeping: 4 loads/group; before consuming a buffer exactly 3
// younger groups (12 loads) are outstanding -> vmcnt(12) retires its group.
// score = |c|^2 + (-2x)·c, acc-init = csqr, 6 MFMAs/tile/mt (hh,lh,hl;
// ll ~2^-24 dropped). Cross-wave merge via LDS (code-half 0 has smaller
// indices -> '<' keeps np.argmin first-min). Epilogue: block-cooperative
// contiguous zq span write (16B-aligned despite out+1).
// ---------------------------------------------------------------------------
__global__ __launch_bounds__(256, 3)
void argmin_kernel(const float* __restrict__ X,
                   const _Float16* __restrict__ CBf,
                   const float* __restrict__ csqr,
                   const float* __restrict__ CB,
                   float* __restrict__ out) {
    __shared__ float LsC[K_CODES];       // csqr copy, 4 KB
    __shared__ float candD[64][2];
    __shared__ int   candI[64][2];
    __shared__ int   ivfin[64];
    __shared__ float xsqW[2];

    const int t    = threadIdx.x;
    const int wave = t >> 6;
    const int lane = t & 63;
    const int lrow = lane & 15;
    const int quad = lane >> 4;
    const int rh   = wave >> 1;          // row half
    const int ch   = wave & 1;           // code half
    const int R0   = blockIdx.x * 64;
    const int Rw   = R0 + rh * 32;

    // Stage csqr to LDS (covered by the barrier below).
    ((float4*)LsC)[t] = ((const float4*)csqr)[t];

    // ---- A fragments: (-2x) split hi/lo; xsq accumulated (ch==0 waves
    // contribute so each block element is counted exactly once).
    // A layout: lane holds A[m=lane&15][k=quad*8+j], j=0..7.
    f16x8 Ah[2][2], Al[2][2];
    float xsq = 0.0f;
#pragma unroll
    for (int mt = 0; mt < 2; ++mt) {
        const float* xr = X + (size_t)(Rw + mt * 16 + lrow) * D;
#pragma unroll
        for (int ks = 0; ks < 2; ++ks) {
            const int k0 = ks * 32 + quad * 8;
            float4 v0 = *(const float4*)(xr + k0);
            float4 v1 = *(const float4*)(xr + k0 + 4);
            float xs[8] = {v0.x, v0.y, v0.z, v0.w, v1.x, v1.y, v1.z, v1.w};
            f16x8 h, l;
#pragma unroll
            for (int j = 0; j < 8; ++j) {
                xsq += xs[j] * xs[j];
                float sv = -2.0f * xs[j];
                _Float16 hh = (_Float16)sv;
                h[j] = hh;
                l[j] = (_Float16)(sv - (float)hh);
            }
            Ah[mt][ks] = h;
            Al[mt][ks] = l;
        }
    }
    __syncthreads();   // LsC ready (A-load vmcnt drained by compiler here)

    float bestd[2][4];
    int   besti[2][4];
#pragma unroll
    for (int mt = 0; mt < 2; ++mt)
#pragma unroll
        for (int r = 0; r < 4; ++r) { bestd[mt][r] = 3.0e38f; besti[mt][r] = 0; }

    // Wave's code range starts at tile ch*32.
    const f16x8* gw = (const f16x8*)CBf + (size_t)ch * 32 * 256 + lane;

// Inline-asm load group: 4x dwordx4, byte offsets 0/1024/2048/3072 from the
// per-tile base. Early-clobber outs so the addr pair is never overwritten.
#define ALOAD(Bv, tl)                                                         \
    do {                                                                      \
        const f16x8* _p = gw + (size_t)(tl) * 256;                            \
        asm volatile(                                                         \
            "global_load_dwordx4 %0, %4, off\n\t"                             \
            "global_load_dwordx4 %1, %4, off offset:1024\n\t"                 \
            "global_load_dwordx4 %2, %4, off offset:2048\n\t"                 \
            "global_load_dwordx4 %3, %4, off offset:3072"                     \
            : "=&v"(Bv[0]), "=&v"(Bv[1]), "=&v"(Bv[2]), "=&v"(Bv[3])          \
            : "v"(_p));                                                       \
    } while (0)

// Wait until this buffer's group retired (3 younger groups = 12 loads may
// remain). Data-tied (+v) so consuming MFMAs cannot float above the wait.
#define WAITB(Bv)                                                             \
    asm volatile("s_waitcnt vmcnt(12)"                                        \
                 : "+v"(Bv[0]), "+v"(Bv[1]), "+v"(Bv[2]), "+v"(Bv[3]))

#define COMPUTE(Bv, tl)                                                       \
    do {                                                                      \
        const int   c  = (ch * 32 + (tl)) * 16 + lrow;                        \
        const float cs = LsC[c];                                              \
        _Pragma("unroll")                                                     \
        for (int mt = 0; mt < 2; ++mt) {                                      \
            f32x4 acc = {cs, cs, cs, cs};                                     \
            acc = MFMA16(Ah[mt][0], Bv[0], acc);                              \
            acc = MFMA16(Ah[mt][1], Bv[1], acc);                              \
            acc = MFMA16(Al[mt][0], Bv[0], acc);                              \
            acc = MFMA16(Al[mt][1], Bv[1], acc);                              \
            acc = MFMA16(Ah[mt][0], Bv[2], acc);                              \
            acc = MFMA16(Ah[mt][1], Bv[3], acc);                              \
            _Pragma("unroll")                                                 \
            for (int r = 0; r < 4; ++r) {                                     \
                bool lt = acc[r] < bestd[mt][r];                              \
                bestd[mt][r] = lt ? acc[r] : bestd[mt][r];                    \
                besti[mt][r] = lt ? c : besti[mt][r];                         \
            }                                                                 \
        }                                                                     \
    } while (0)

    // 32 local tiles, 4-buffer asm pipeline, distance-3. Overrun loads wrap
    // via &31 (reloaded, never computed) so all stay inside CBf. Codes
    // ascend with tl for fixed lane -> strict < keeps np.argmin first-min.
    f16x8 B0[4], B1[4], B2[4], B3[4];
    ALOAD(B0, 0);
    ALOAD(B1, 1);
    ALOAD(B2, 2);
    for (int tl = 0; tl < 32; tl += 4) {
        ALOAD(B3, (tl + 3) & 31);
        WAITB(B0);
        COMPUTE(B0, tl);
        ALOAD(B0, (tl + 4) & 31);
        WAITB(B1);
        COMPUTE(B1, tl + 1);
        ALOAD(B1, (tl + 5) & 31);
        WAITB(B2);
        COMPUTE(B2, tl + 2);
        ALOAD(B2, (tl + 6) & 31);
        WAITB(B3);
        COMPUTE(B3, tl + 3);
    }
    // Drain all in-flight asm loads before their dest regs can be reused.
    asm volatile("s_waitcnt vmcnt(0)"
                 :
                 : "v"(B0[0]), "v"(B0[1]), "v"(B0[2]), "v"(B0[3]),
                   "v"(B1[0]), "v"(B1[1]), "v"(B1[2]), "v"(B1[3]),
                   "v"(B2[0]), "v"(B2[1]), "v"(B2[2]), "v"(B2[3]),
                   "v"(B3[0]), "v"(B3[1]), "v"(B3[2]), "v"(B3[3])
                 : "memory");

    // ---- xsq: reduce within ch==0 waves (each block element once).
    if (ch == 0) {
        float s = xsq;
#pragma unroll
        for (int m = 1; m < 64; m <<= 1) s += __shfl_xor(s, m, 64);
        if (lane == 0) xsqW[rh] = s;
    }

    // ---- In-wave argmin reduce across the 16 code-columns (lexicographic
    // on exact ties), deposit per-row candidate for this code half.
#pragma unroll
    for (int mt = 0; mt < 2; ++mt) {
#pragma unroll
        for (int r = 0; r < 4; ++r) {
            float dv = bestd[mt][r];
            int   iv = besti[mt][r];
#pragma unroll
            for (int m = 1; m < 16; m <<= 1) {
                float od = __shfl_xor(dv, m, 64);
                int   oi = __shfl_xor(iv, m, 64);
                if (od < dv || (od == dv && oi < iv)) { dv = od; iv = oi; }
            }
            if (lrow == 0) {
                int rl = rh * 32 + mt * 16 + quad * 4 + r;   // 0..63
                candD[rl][ch] = dv;
                candI[rl][ch] = iv;
            }
        }
    }
    __syncthreads();

    // ---- Merge the two code halves; write idxf; accumulate loss.
    const float scale = 1.25f / (float)((size_t)N_ROWS * D);
    if (t < 64) {
        float d0 = candD[t][0], d1 = candD[t][1];
        int   i0 = candI[t][0], i1 = candI[t][1];
        // ch0 indices are all < ch1 indices -> tie keeps ch0 (first min).
        bool take1 = d1 < d0;
        float dv = take1 ? d1 : d0;
        int   iv = take1 ? i1 : i0;
        out[1 + (size_t)N_ROWS * D + R0 + t] = (float)iv;   // idxf
        ivfin[t] = iv;
        float ssum = dv;
#pragma unroll
        for (int m = 1; m < 64; m <<= 1) ssum += __shfl_xor(ssum, m, 64);
        if (t == 0)
            atomicAdd(out, (ssum + xsqW[0] + xsqW[1]) * scale);
    }
    __syncthreads();

    // ---- Block-cooperative zq span write: dwords [R0*64, R0*64+4096) at
    // out+1. Global dword offset 1+R0*64+j is 16B-aligned iff j%4==3.
    float* p = out + 1 + (size_t)R0 * D;
#pragma unroll
    for (int i = 0; i < 4; ++i) {
        int q = i * 256 + t;        // 0..1023
        int j = 4 * q + 3;          // 3,7,...,4095
        if (q < 1023) {
            float v[4];
#pragma unroll
            for (int e = 0; e < 4; ++e) {
                int jj = j + e;     // may straddle a row boundary
                v[e] = CB[(size_t)ivfin[jj >> 6] * D + (jj & 63)];
            }
            *(float4*)(p + j) = make_float4(v[0], v[1], v[2], v[3]);
        } else if (q == 1023) {
            p[4095] = CB[(size_t)ivfin[63] * D + 63];
        }
    }
    if (t == 0) {   // head dwords j=0..2 (row 0, cols 0..2)
        const float* c0 = CB + (size_t)ivfin[0] * D;
        p[0] = c0[0];
        p[1] = c0[1];
        p[2] = c0[2];
    }
}

// ---------------------------------------------------------------------------
extern "C" void kernel_launch(void* const* d_in, const int* in_sizes, int n_in,
                              void* d_out, int out_size, void* d_ws,
                              size_t ws_size, hipStream_t stream) {
    const float* X  = (const float*)d_in[0];   // inputs  [131072,64]
    const float* CB = (const float*)d_in[1];   // codebook [1024,64]

    float*    csqr = (float*)d_ws;                      // 4 KB
    _Float16* CBf  = (_Float16*)((char*)d_ws + 4096);   // 256 KB

    hipLaunchKernelGGL(prep_kernel, dim3(65), dim3(256), 0, stream,
                       CB, CBf, csqr, (float*)d_out);
    hipLaunchKernelGGL(argmin_kernel, dim3(N_ROWS / 64), dim3(256), 0, stream,
                       X, CBf, csqr, CB, (float*)d_out);
}